// Round 1
// 1331.668 us; speedup vs baseline: 6.1012x; 6.1012x over previous
//
#include <hip/hip_runtime.h>

// V2: fused 3x(3x3 conv) + ReLU via implicit-GEMM MFMA (bf16 in, f32 acc).
// One block per 32x32 output tile. Activations staged in LDS as [y][x][ci]
// bf16 so an MFMA B-fragment (8 consecutive ci at one pixel) is a single
// ds_read_b128. Per 16-position tile: 16co x 16pos output, K=32 packs
// (ci-half, tap-pair); 9 taps -> 5 MFMAs (10th K-slot has zero weights).
// conv1 (3ci x 9taps = K27, padded to 32) is one MFMA with 8x ds_read_u16
// register im2col. Weight A-fragments pre-gathered per block into VGPRs
// (bf16) -> no in-loop s_load stalls. h1/h2 values at out-of-image
// positions are zeroed (SAME-padding semantics), matching the reference.

#define HH 1536
#define WW 1536
#define BB 4
#define TS 32        // output tile edge
#define NT (HH / TS) // 48

typedef __attribute__((ext_vector_type(8))) short short8;
typedef __attribute__((ext_vector_type(4))) float f32x4;
typedef __attribute__((ext_vector_type(2))) unsigned int u32x2;

__device__ __forceinline__ unsigned short f2b(float f) {
    union { float f; unsigned u; } v; v.f = f;
    unsigned r = v.u + 0x7FFFu + ((v.u >> 16) & 1u); // RNE
    return (unsigned short)(r >> 16);
}

extern "C" __global__ __launch_bounds__(512, 4)
void fused_conv3(const float* __restrict__ x,
                 const float* __restrict__ w1,
                 const float* __restrict__ w2,
                 const float* __restrict__ w3,
                 float* __restrict__ out)
{
    // h1: 36x36 positions x 16 ci, [y][x][ci] bf16 = 41472 B
    __shared__ unsigned short sh1[36 * 36 * 16];
    // union: x-stage [ci][38][38] bf16 (8664 B) / h2 [y][x][ci] (36992 B)
    __shared__ unsigned short sxh2[34 * 34 * 16];

    const int tid  = threadIdx.x;
    const int lane = tid & 63;
    const int wid  = tid >> 6;   // 8 waves
    const int blk  = blockIdx.x;
    const int b    = blk / (NT * NT);
    const int rr_  = blk % (NT * NT);
    const int ty   = rr_ / NT, tx = rr_ % NT;
    const int y0   = ty * TS, x0 = tx * TS;

    const int m  = lane & 15;   // A row (co) == B col (position) == D col
    const int g4 = lane >> 4;   // 0..3 : k-block of 8
    const int h  = g4 & 1;      // ci half (0: ci 0-7, 1: ci 8-15)
    const int s  = lane >> 5;   // tap-pair selector
    const int kb = g4 * 8;      // k base within K=32

    // ---- build weight A-fragments + per-lane LDS gather offsets (once) ----
    // conv1: k = ci*9 + tap (27 real, 5 zero-pad)
    short8 w1f;
    int offs1[8]; // short-unit offsets into x-stage [ci][38][38]
#pragma unroll
    for (int i = 0; i < 8; ++i) {
        int k = kb + i;
        if (k < 27) {
            int ci = k / 9, off = k - ci * 9;
            int dy = off / 3, dx = off - dy * 3;
            w1f[i]   = (short)f2b(w1[m * 27 + k]);
            offs1[i] = ci * (38 * 38) + dy * 38 + dx;
        } else { w1f[i] = 0; offs1[i] = 0; }
    }
    // conv2/conv3: MFMA j covers taps (2j+0, 2j+1); k = s*16 + h*8 + i,
    // ci = h*8+i, tap o = 2j+s (j=4,s=1 is the zero-weight pad slot).
    short8 w2f[5], w3f[5];
    int boff2[5], boff3[5]; // short-unit displacement of the b128 read
#pragma unroll
    for (int j = 0; j < 5; ++j) {
        int o = 2 * j + s;
        int zero = (o > 8) ? 1 : 0;
        if (zero) o = 8;               // valid address, zero weights
        int dy = o / 3, dx = o - dy * 3;
#pragma unroll
        for (int i = 0; i < 8; ++i) {
            int ci = h * 8 + i;
            w2f[j][i] = zero ? (short)0 : (short)f2b(w2[(m * 16 + ci) * 9 + o]);
            w3f[j][i] = zero ? (short)0 : (short)f2b(w3[(m * 16 + ci) * 9 + o]);
        }
        boff2[j] = (dy * 36 + dx) * 16 + h * 8;
        boff3[j] = (dy * 34 + dx) * 16 + h * 8;
    }

    // ---- phase 0: stage x tile (3 x 38 x 38, halo 3, zero-padded) ----
    {
        const float* xb = x + (size_t)b * 3 * HH * WW;
        for (int i = tid; i < 3 * 38 * 38; i += 512) {
            int c  = i / 1444;
            int r2 = i - c * 1444;
            int yy = r2 / 38, xx = r2 - yy * 38;
            int gy = y0 - 3 + yy, gx = x0 - 3 + xx;
            float v = 0.f;
            if ((unsigned)gy < (unsigned)HH && (unsigned)gx < (unsigned)WW)
                v = xb[(size_t)c * (HH * WW) + (size_t)gy * WW + gx];
            sxh2[i] = f2b(v);
        }
    }
    __syncthreads();

    // ---- phase 1: conv1 -> h1 at 36x36 (halo 2). 81 exact 16-pos tiles ----
    for (int t = wid; t < 81; t += 8) {
        int p = t * 16 + m;                       // 0..1295
        unsigned yy = (unsigned)p / 36u;
        unsigned xx = (unsigned)p - yy * 36u;
        int base = (int)(yy * 38u + xx);
        short8 bf;
#pragma unroll
        for (int i = 0; i < 8; ++i)
            bf[i] = (short)sxh2[base + offs1[i]]; // ds_read_u16 im2col
        f32x4 acc = {0.f, 0.f, 0.f, 0.f};
        acc = __builtin_amdgcn_mfma_f32_16x16x32_bf16(w1f, bf, acc, 0, 0, 0);
        int gy = y0 - 2 + (int)yy, gx = x0 - 2 + (int)xx;
        float msk = ((unsigned)gy < (unsigned)HH && (unsigned)gx < (unsigned)WW)
                        ? 1.f : 0.f;              // h1 outside image := 0
        u32x2 pk;
        pk.x = (unsigned)f2b(acc[0] * msk) | ((unsigned)f2b(acc[1] * msk) << 16);
        pk.y = (unsigned)f2b(acc[2] * msk) | ((unsigned)f2b(acc[3] * msk) << 16);
        *(u32x2*)&sh1[(yy * 36u + xx) * 16u + (unsigned)(g4 * 4)] = pk;
    }
    __syncthreads();

    // ---- phase 2: conv2 -> h2 at 34x34 (halo 1). 73 tiles (last partial) ----
    for (int t = wid; t < 73; t += 8) {
        int p  = t * 16 + m;                      // 0..1167, valid < 1156
        int pc = p < 1155 ? p : 1155;             // clamp B-loads in-range
        unsigned yy = (unsigned)pc / 34u;
        unsigned xx = (unsigned)pc - yy * 34u;
        int base = (int)((yy * 36u + xx) * 16u);
        f32x4 acc = {0.f, 0.f, 0.f, 0.f};
#pragma unroll
        for (int j = 0; j < 5; ++j) {
            short8 bfr = *(const short8*)&sh1[base + boff2[j]]; // ds_read_b128
            acc = __builtin_amdgcn_mfma_f32_16x16x32_bf16(w2f[j], bfr, acc, 0, 0, 0);
        }
        if (p < 1156) {
            int gy = y0 - 1 + (int)yy, gx = x0 - 1 + (int)xx;
            float msk = ((unsigned)gy < (unsigned)HH && (unsigned)gx < (unsigned)WW)
                            ? 1.f : 0.f;
            u32x2 pk;
            pk.x = (unsigned)f2b(acc[0] * msk) | ((unsigned)f2b(acc[1] * msk) << 16);
            pk.y = (unsigned)f2b(acc[2] * msk) | ((unsigned)f2b(acc[3] * msk) << 16);
            *(u32x2*)&sxh2[(yy * 34u + xx) * 16u + (unsigned)(g4 * 4)] = pk;
        }
    }
    __syncthreads();

    // ---- phase 3: conv3 + ReLU at 32x32, write global. 64 exact tiles ----
    for (int t = wid; t < 64; t += 8) {
        int p  = t * 16 + m;
        int yy = p >> 5, xx = p & 31;
        int base = (yy * 34 + xx) * 16;
        f32x4 acc = {0.f, 0.f, 0.f, 0.f};
#pragma unroll
        for (int j = 0; j < 5; ++j) {
            short8 bfr = *(const short8*)&sxh2[base + boff3[j]];
            acc = __builtin_amdgcn_mfma_f32_16x16x32_bf16(w3f[j], bfr, acc, 0, 0, 0);
        }
        int gy = y0 + yy, gx = x0 + xx;
        float* op = out + (((size_t)b * 16 + g4 * 4) * HH + gy) * (size_t)WW + gx;
#pragma unroll
        for (int r = 0; r < 4; ++r) {
            float v = acc[r] > 0.f ? acc[r] : 0.f;
            op[(size_t)r * (HH * WW)] = v;
        }
    }
}

extern "C" void kernel_launch(void* const* d_in, const int* in_sizes, int n_in,
                              void* d_out, int out_size, void* d_ws, size_t ws_size,
                              hipStream_t stream) {
    const float* x  = (const float*)d_in[0];
    const float* w1 = (const float*)d_in[1];
    const float* w2 = (const float*)d_in[2];
    const float* w3 = (const float*)d_in[3];
    float* out = (float*)d_out;
    dim3 grid(BB * NT * NT);  // 9216 blocks
    dim3 block(512);
    fused_conv3<<<grid, block, 0, stream>>>(x, w1, w2, w3, out);
}

// Round 2
// 874.101 us; speedup vs baseline: 9.2950x; 1.5235x over previous
//
#include <hip/hip_runtime.h>

// V3: fused 3x(3x3 conv) + ReLU, implicit-GEMM MFMA (bf16 in, f32 acc).
// Changes vs V2:
//  - TS=24 tile -> LDS 46.7KB -> 3 blocks/CU (24 waves, was 2 blocks/48KB+).
//  - Weight A-fragments pre-packed by a tiny prep kernel into d_ws; main
//    kernel loads them with coalesced dwordx4 (per phase, low VGPR).
//  - x staged as [30][30][4ci] bf16 so conv1 is 3x ds_read_b64 + 2 MFMAs
//    per 16 positions (was 8x ds_read_u16 im2col + repack).
//  - h1/h2 stored with XOR swizzle on the 16B granule (u = pos*2+h,
//    u ^= (pos>>2)&1) -> conflict-free ds_read_b128 (write+read both swizzled).
// Zero-weight pad slots always read valid (finite) LDS; garbage*0 avoided.

#define HH 1536
#define WW 1536
#define BB 4
#define TS 24
#define NT (HH / TS)   // 64
#define SXW 30         // x-stage edge  [30][30][4]
#define H1W 28         // h1 edge       [28*28][16]
#define H2W 26         // h2 edge       [26*26][16]

typedef __attribute__((ext_vector_type(8))) short short8;
typedef __attribute__((ext_vector_type(4))) float f32x4;
typedef __attribute__((ext_vector_type(2))) unsigned int u32x2;
typedef unsigned long long u64;

__device__ __forceinline__ unsigned short f2b(float f) {
    union { float f; unsigned u; } v; v.f = f;
    unsigned r = v.u + 0x7FFFu + ((v.u >> 16) & 1u); // RNE
    return (unsigned short)(r >> 16);
}

// ---- prep: pack per-lane bf16 A-fragments into ws ----
// slots (each [64 lanes] x short8): 0 = w1f0 (taps dx0,1), 1 = w1f1 (tap dx2),
// 2..6 = w2f[j], 7..11 = w3f[j]
extern "C" __global__ void prep_weights(const float* __restrict__ w1,
                                        const float* __restrict__ w2,
                                        const float* __restrict__ w3,
                                        unsigned short* __restrict__ ws)
{
    const int lane = threadIdx.x & 63;
    const int m = lane & 15, g4 = lane >> 4, h = g4 & 1, s = g4 >> 1;
    // slot 0: conv1 MFMA0: k=g4*8+i -> dy=g4, dx=i>>2 (0..1), ci=i&3
#pragma unroll
    for (int i = 0; i < 8; ++i) {
        int ci = i & 3, dx = i >> 2;
        float v = (g4 < 3 && ci < 3) ? w1[((m * 3 + ci) * 3 + g4) * 3 + dx] : 0.f;
        ws[(0 * 64 + lane) * 8 + i] = f2b(v);
    }
    // slot 1: conv1 MFMA1: dy=g4, dx=2, ci=i (i<3)
#pragma unroll
    for (int i = 0; i < 8; ++i) {
        float v = (g4 < 3 && i < 3) ? w1[((m * 3 + i) * 3 + g4) * 3 + 2] : 0.f;
        ws[(1 * 64 + lane) * 8 + i] = f2b(v);
    }
    // slots 2..6 / 7..11: conv2/conv3: k=g4*8+i -> tap o=2j+s, ci=h*8+i
#pragma unroll
    for (int j = 0; j < 5; ++j) {
        int o = 2 * j + s;
        int zero = (o > 8);
#pragma unroll
        for (int i = 0; i < 8; ++i) {
            int ci = h * 8 + i;
            float v2 = zero ? 0.f : w2[(m * 16 + ci) * 9 + o];
            float v3 = zero ? 0.f : w3[(m * 16 + ci) * 9 + o];
            ws[((2 + j) * 64 + lane) * 8 + i] = f2b(v2);
            ws[((7 + j) * 64 + lane) * 8 + i] = f2b(v3);
        }
    }
}

extern "C" __global__ __launch_bounds__(512, 6)
void fused_conv3(const float* __restrict__ x,
                 const unsigned short* __restrict__ wsw,
                 float* __restrict__ out)
{
    __shared__ unsigned short sh1[H1W * H1W * 16];   // 25088 B
    __shared__ unsigned short sxh2[H2W * H2W * 16];  // 21632 B (union: x-stage 30*30*4=7200 B)

    const int tid  = threadIdx.x;
    const int lane = tid & 63;
    const int wid  = tid >> 6;   // 8 waves
    const int blk  = blockIdx.x;
    const int b    = blk / (NT * NT);
    const int rr_  = blk % (NT * NT);
    const int ty   = rr_ / NT, tx = rr_ % NT;
    const int y0   = ty * TS, x0 = tx * TS;

    const int m  = lane & 15;
    const int g4 = lane >> 4;
    const int h  = g4 & 1;
    const int s  = g4 >> 1;

    const short8* wf = (const short8*)wsw;
    short8 w1f0 = wf[0 * 64 + lane];
    short8 w1f1 = wf[1 * 64 + lane];

    // per-lane tap displacements for conv2/conv3 (o=2j+s, pad slot clamps to 8)
    int disp2[5], disp3[5];
#pragma unroll
    for (int j = 0; j < 5; ++j) {
        int o = 2 * j + s; if (o > 8) o = 8;
        int dy = o / 3, dx = o - dy * 3;
        disp2[j] = dy * H1W + dx;
        disp3[j] = dy * H2W + dx;
    }

    // ---- phase 0: stage x tile [30][30][4] bf16 (halo 3, zero-padded) ----
    {
        const float* xb = x + (size_t)b * 3 * HH * WW;
        for (int i = tid; i < SXW * SXW; i += 512) {
            int py = i / SXW, px = i - py * SXW;
            int gy = y0 - 3 + py, gx = x0 - 3 + px;
            unsigned short p0 = 0, p1 = 0, p2 = 0;
            if ((unsigned)gy < (unsigned)HH && (unsigned)gx < (unsigned)WW) {
                size_t o = (size_t)gy * WW + gx;
                p0 = f2b(xb[o]);
                p1 = f2b(xb[o + (size_t)HH * WW]);
                p2 = f2b(xb[o + 2 * (size_t)HH * WW]);
            }
            u64 pk = (u64)p0 | ((u64)p1 << 16) | ((u64)p2 << 32);
            *(u64*)&sxh2[i * 4] = pk;
        }
    }
    __syncthreads();

    // ---- phase 1: conv1 -> h1 at 28x28 (49 exact 16-pos tiles) ----
    {
        const int dyc = (g4 < 3) ? g4 : 2;  // g4=3: zero weights, valid addr
        for (int t = wid; t < 49; t += 8) {
            int p  = t * 16 + m;            // 0..783 == py*28+px
            int py = p / H1W, px = p - py * H1W;
            int pixb = (py + dyc) * SXW + px;
            short8 bf0, bf1;
            ((u64*)&bf0)[0] = *(const u64*)&sxh2[pixb * 4];
            ((u64*)&bf0)[1] = *(const u64*)&sxh2[(pixb + 1) * 4];
            ((u64*)&bf1)[0] = *(const u64*)&sxh2[(pixb + 2) * 4];
            ((u64*)&bf1)[1] = 0;
            f32x4 acc = {0.f, 0.f, 0.f, 0.f};
            acc = __builtin_amdgcn_mfma_f32_16x16x32_bf16(w1f0, bf0, acc, 0, 0, 0);
            acc = __builtin_amdgcn_mfma_f32_16x16x32_bf16(w1f1, bf1, acc, 0, 0, 0);
            int gy = y0 - 2 + py, gx = x0 - 2 + px;
            float msk = ((unsigned)gy < (unsigned)HH && (unsigned)gx < (unsigned)WW)
                            ? 1.f : 0.f;    // h1 outside image := 0
            u32x2 pk;
            pk.x = (unsigned)f2b(acc[0] * msk) | ((unsigned)f2b(acc[1] * msk) << 16);
            pk.y = (unsigned)f2b(acc[2] * msk) | ((unsigned)f2b(acc[3] * msk) << 16);
            unsigned uw = (unsigned)(p << 1) + (unsigned)((g4 >> 1) ^ ((p >> 2) & 1));
            *(u32x2*)&sh1[uw * 8 + (g4 & 1) * 4] = pk;
        }
    }
    short8 w2f[5];
#pragma unroll
    for (int j = 0; j < 5; ++j) w2f[j] = wf[(2 + j) * 64 + lane];
    __syncthreads();

    // ---- phase 2: conv2 -> h2 at 26x26 (43 tiles, last partial) ----
    for (int t = wid; t < 43; t += 8) {
        int p  = t * 16 + m;                // valid < 676
        int pc = p < 675 ? p : 675;
        int py = pc / H2W, px = pc - py * H2W;
        int posb = py * H1W + px;
        f32x4 acc = {0.f, 0.f, 0.f, 0.f};
#pragma unroll
        for (int j = 0; j < 5; ++j) {
            int pr = posb + disp2[j];
            unsigned ur = (unsigned)(pr << 1) + (unsigned)(h ^ ((pr >> 2) & 1));
            short8 bfr = *(const short8*)&sh1[ur * 8];
            acc = __builtin_amdgcn_mfma_f32_16x16x32_bf16(w2f[j], bfr, acc, 0, 0, 0);
        }
        if (p < 676) {
            int gy = y0 - 1 + py, gx = x0 - 1 + px;
            float msk = ((unsigned)gy < (unsigned)HH && (unsigned)gx < (unsigned)WW)
                            ? 1.f : 0.f;
            u32x2 pk;
            pk.x = (unsigned)f2b(acc[0] * msk) | ((unsigned)f2b(acc[1] * msk) << 16);
            pk.y = (unsigned)f2b(acc[2] * msk) | ((unsigned)f2b(acc[3] * msk) << 16);
            unsigned uw = (unsigned)(p << 1) + (unsigned)((g4 >> 1) ^ ((p >> 2) & 1));
            *(u32x2*)&sxh2[uw * 8 + (g4 & 1) * 4] = pk;
        }
    }
    short8 w3f[5];
#pragma unroll
    for (int j = 0; j < 5; ++j) w3f[j] = wf[(7 + j) * 64 + lane];
    __syncthreads();

    // ---- phase 3: conv3 + ReLU at 24x24 (36 exact tiles), write global ----
    for (int t = wid; t < 36; t += 8) {
        int p  = t * 16 + m;                // 0..575
        int oy = p / TS, ox = p - oy * TS;
        int posb = oy * H2W + ox;
        f32x4 acc = {0.f, 0.f, 0.f, 0.f};
#pragma unroll
        for (int j = 0; j < 5; ++j) {
            int pr = posb + disp3[j];
            unsigned ur = (unsigned)(pr << 1) + (unsigned)(h ^ ((pr >> 2) & 1));
            short8 bfr = *(const short8*)&sxh2[ur * 8];
            acc = __builtin_amdgcn_mfma_f32_16x16x32_bf16(w3f[j], bfr, acc, 0, 0, 0);
        }
        int gy = y0 + oy, gx = x0 + ox;
        float* op = out + (((size_t)b * 16 + g4 * 4) * HH + gy) * (size_t)WW + gx;
#pragma unroll
        for (int r = 0; r < 4; ++r) {
            float v = acc[r] > 0.f ? acc[r] : 0.f;
            op[(size_t)r * (HH * WW)] = v;
        }
    }
}

extern "C" void kernel_launch(void* const* d_in, const int* in_sizes, int n_in,
                              void* d_out, int out_size, void* d_ws, size_t ws_size,
                              hipStream_t stream) {
    const float* x  = (const float*)d_in[0];
    const float* w1 = (const float*)d_in[1];
    const float* w2 = (const float*)d_in[2];
    const float* w3 = (const float*)d_in[3];
    float* out = (float*)d_out;
    unsigned short* ws = (unsigned short*)d_ws;  // 12 slots * 64 lanes * 16B = 12 KiB
    prep_weights<<<dim3(1), dim3(64), 0, stream>>>(w1, w2, w3, ws);
    dim3 grid(BB * NT * NT);  // 16384 blocks
    dim3 block(512);
    fused_conv3<<<grid, block, 0, stream>>>(x, ws, out);
}